// Round 8
// baseline (297.968 us; speedup 1.0000x reference)
//
#include <hip/hip_runtime.h>
#include <math.h>

#define HD  256
#define BM  16
#define NTH 256

typedef __attribute__((ext_vector_type(8))) short bf16x8;
typedef __attribute__((ext_vector_type(4))) float f32x4;

__device__ __forceinline__ float rcp_f(float x){ return __builtin_amdgcn_rcpf(x); }
__device__ __forceinline__ float tanh_f(float x){
  float ax = fabsf(x);
  float e  = __expf(-2.f*ax);
  float t  = (1.f - e) * rcp_f(1.f + e);
  return copysignf(t, x);
}
__device__ __forceinline__ float artanh_f(float v){
  v = fminf(fmaxf(v, -1.f + 1e-7f), 1.f - 1e-7f);
  return 0.5f * __logf((1.f + v) * rcp_f(1.f - v));
}
__device__ __forceinline__ float sigmoid_f(float v){ return rcp_f(1.f + __expf(-v)); }
__device__ __forceinline__ unsigned short f2bf(float f){
  unsigned u = __float_as_uint(f);
  u += 0x7FFFu + ((u >> 16) & 1u);
  return (unsigned short)(u >> 16);
}
__device__ __forceinline__ float bf2f(unsigned short h){
  return __uint_as_float(((unsigned)h) << 16);
}
__device__ __forceinline__ int swz(int R, int C){
  return R*HD + (((C >> 3) ^ (R & 7)) << 3) + (C & 7);
}

// ---- W fp32 -> bf16 in MFMA-fragment order ----
__global__ void convert_w_kernel(const float* __restrict__ Wih,
                                 const float* __restrict__ Whh,
                                 unsigned short* __restrict__ wb){
  int c = blockIdx.x * blockDim.x + threadIdx.x;
  if (c >= 6 * 8192) return;
  int mat = c >> 13;
  int ci  = c & 8191;
  int l = ci & 63, st = ci >> 6;
  int s = st & 7, ct = st >> 3;
  int col = ct * 16 + (l & 15);
  int k0  = s * 32 + (l >> 4) * 8;
  const float* src = (mat < 3) ? (Wih + (size_t)mat * HD * HD)
                               : (Whh + (size_t)(mat - 3) * HD * HD);
  const float* p = src + (size_t)col * HD + k0;
  unsigned short tmp[8];
  #pragma unroll
  for (int j = 0; j < 8; ++j) tmp[j] = f2bf(p[j]);
  *(bf16x8*)(wb + (size_t)mat * 65536 + (size_t)ci * 8) = *(bf16x8*)tmp;
}

// ---- dual GEMM for one gate; per-wave 16x64 tile (4 waves cover 16x256) ----
__device__ __forceinline__ void gate_gemm(
    const unsigned short* ldsH, const unsigned short* __restrict__ wH,
    const unsigned short* ldsX, const unsigned short* __restrict__ wX,
    f32x4 A[4], f32x4 Bx[4], int wc, int lr, int lg, int l){
  #pragma unroll
  for (int n = 0; n < 4; ++n){
    A[n]  = (f32x4){0.f,0.f,0.f,0.f};
    Bx[n] = (f32x4){0.f,0.f,0.f,0.f};
  }
  #pragma unroll
  for (int s = 0; s < 8; ++s){
    int idx = lr*HD + (((4*s + lg) ^ (lr & 7)) << 3);
    bf16x8 ah = *(const bf16x8*)&ldsH[idx];
    bf16x8 ax = *(const bf16x8*)&ldsX[idx];
    #pragma unroll
    for (int n = 0; n < 4; ++n){
      int ct = wc*4 + n;
      int off = ((ct*8 + s)*64 + l)*8;
      bf16x8 bh = *(const bf16x8*)(wH + off);
      bf16x8 bx = *(const bf16x8*)(wX + off);
      A[n]  = __builtin_amdgcn_mfma_f32_16x16x32_bf16(ah, bh, A[n], 0, 0, 0);
      Bx[n] = __builtin_amdgcn_mfma_f32_16x16x32_bf16(ax, bx, Bx[n], 0, 0, 0);
    }
  }
}

// ---- 7-value row reduction + once-per-row chain -> kco[R]={KA,KB,Kb,mu,is} ----
__device__ __forceinline__ void gate_reduce_chain(
    const f32x4 (&A)[4], const f32x4 (&Bx)[4], const float (&bt)[4],
    float (*RED)[33], float (*kco)[9], float (*srow)[BM], const float* sbb,
    int rowA, int gidx, int t, int wc, int lr, int lg){
  float p[7][4];
  #pragma unroll
  for (int q = 0; q < 4; ++q){
    float a2=0.f,b2=0.f,ab=0.f,sA=0.f,sB=0.f,Ab=0.f,Bb=0.f;
    #pragma unroll
    for (int n = 0; n < 4; ++n){
      float ae = A[n][q], be = Bx[n][q], bv = bt[n];
      a2 = fmaf(ae,ae,a2); b2 = fmaf(be,be,b2); ab = fmaf(ae,be,ab);
      sA += ae; sB += be; Ab = fmaf(ae,bv,Ab); Bb = fmaf(be,bv,Bb);
    }
    p[0][q]=a2; p[1][q]=b2; p[2][q]=ab; p[3][q]=sA; p[4][q]=sB; p[5][q]=Ab; p[6][q]=Bb;
  }
  #pragma unroll
  for (int j = 0; j < 7; ++j)
    #pragma unroll
    for (int q = 0; q < 4; ++q){
      float v = p[j][q];
      v += __shfl_xor(v,1); v += __shfl_xor(v,2);
      v += __shfl_xor(v,4); v += __shfl_xor(v,8);
      p[j][q] = v;
    }
  if (lr == 0){
    #pragma unroll
    for (int q = 0; q < 4; ++q){
      int R = lg*4 + q;
      #pragma unroll
      for (int j = 0; j < 7; ++j) RED[R][wc*8 + j] = p[j][q];
    }
  }
  __syncthreads();
  if (t < BM){
    int R = t;
    float s[7];
    #pragma unroll
    for (int j = 0; j < 7; ++j)
      s[j] = RED[R][j] + RED[R][8+j] + RED[R][16+j] + RED[R][24+j];
    float bb  = sbb[gidx];
    float sbs = sbb[4+gidx];
    float an = srow[rowA][R], aa = srow[rowA+1][R];
    float bn = srow[0][R],    ba = srow[1][R];
    float mraw = sqrtf(s[0]); float mA = fmaxf(mraw, 1e-7f);
    float tA = tanh_f(mA / an * aa);
    float sa  = (mraw <= 1e-7f) ? 0.f : tA / mA;
    float x2a = (mraw <= 1e-7f) ? 0.f : tA*tA;
    float nraw = sqrtf(s[1]); float mB = fmaxf(nraw, 1e-7f);
    float tB = tanh_f(mB / bn * ba);
    float sb_ = (nraw <= 1e-7f) ? 0.f : tB / mB;
    float x2b = (nraw <= 1e-7f) ? 0.f : tB*tB;
    float xy = sa*sb_*s[2];
    float ca = 1.f + 2.f*xy + x2b;
    float cb = 1.f - x2a;
    float den = fmaxf(1.f + 2.f*xy + x2a*x2b, 1e-15f);
    float u = ca*sa/den, v = cb*sb_/den;
    float P2 = u*u*s[0] + 2.f*u*v*s[2] + v*v*s[1];
    float Pb = u*s[5] + v*s[6];
    float sP = u*s[3] + v*s[4];
    float ca2 = 1.f + 2.f*Pb + bb;
    float cb2 = 1.f - P2;
    float den2 = fmaxf(1.f + 2.f*Pb + P2*bb, 1e-15f);
    float pp = ca2/den2, ww = cb2/den2;
    float Q2 = pp*pp*P2 + 2.f*pp*ww*Pb + ww*ww*bb;
    float sQsum = pp*sP + ww*sbs;
    float qn = fmaxf(sqrtf(Q2), 1e-7f);
    float sQ = artanh_f(qn) / qn;
    float mu = sQ*sQsum*(1.f/HD);
    float e2 = sQ*sQ*Q2*(1.f/HD);
    float is = rsqrtf(e2 - mu*mu + 1e-5f);
    kco[R][0] = sQ*pp*u;  kco[R][1] = sQ*pp*v;  kco[R][2] = sQ*ww;
    kco[R][3] = mu;       kco[R][4] = is;
  }
  __syncthreads();
}

// R0's proven kernel (221.5us bench) with ONE change: __launch_bounds__(256,3).
// Budget check: 124 arch + 32 acc = 156 <= 2048/(3*4) = 170 -> no spill
// (R6's claim that R0 exceeded the w=3 budget was arithmetic error).
// 3 independent 4-wave barrier-groups/CU instead of 2: group-overlap for
// the serial chains + 1.5x latency hiding, zero other deltas.
__global__ __launch_bounds__(NTH, 3) void mobius_gru_mfma(
    const float* __restrict__ x, const float* __restrict__ hx,
    const unsigned short* __restrict__ wbih, const unsigned short* __restrict__ wbhh,
    const float* __restrict__ bias, const float* __restrict__ gam,
    const float* __restrict__ bet, float* __restrict__ out, int B){
  __shared__ unsigned short xb[BM*HD];
  __shared__ unsigned short hb[BM*HD];
  __shared__ float RED[BM][33];
  __shared__ float kco[BM][9];
  __shared__ float srow[8][BM];   // 0:xn 1:xa 2:hn 3:ha 4:rn 5:ra 6:htn 7:hta
  __shared__ float sbb[8];        // [g]=sum b^2, [4+g]=sum b

  const int t  = threadIdx.x;
  const int l  = t & 63;
  const int lr = l & 15, lg = l >> 4;
  const int wc = t >> 6;          // 4 waves, one 64-col slice each
  const size_t row0 = (size_t)blockIdx.x * BM;

  // ---- stage x,hx -> bf16 swizzled LDS + norm partials (spart overlays RED) ----
  {
    float* spart = &RED[0][0];    // [0,256): x partials, [256,512): h partials
    int r = t >> 4, seg = t & 15;
    const float* xp = x  + (row0 + r)*HD + seg*16;
    const float* hp = hx + (row0 + r)*HD + seg*16;
    float sx = 0.f, sh = 0.f;
    #pragma unroll
    for (int i = 0; i < 4; ++i){
      int c = seg*16 + i*4;
      int di = swz(r, c);
      float4 v = *(const float4*)(xp + i*4);
      sx += v.x*v.x + v.y*v.y + v.z*v.z + v.w*v.w;
      ushort4 o = { f2bf(v.x), f2bf(v.y), f2bf(v.z), f2bf(v.w) };
      *(ushort4*)&xb[di] = o;
      v = *(const float4*)(hp + i*4);
      sh += v.x*v.x + v.y*v.y + v.z*v.z + v.w*v.w;
      ushort4 o2 = { f2bf(v.x), f2bf(v.y), f2bf(v.z), f2bf(v.w) };
      *(ushort4*)&hb[di] = o2;
    }
    spart[r*16 + seg] = sx; spart[256 + r*16 + seg] = sh;
  }
  if (t >= 64 && t < 256){
    int g = (t >> 6) - 1;
    float4 b4 = *(const float4*)&bias[g*HD + (t & 63)*4];
    float p2 = b4.x*b4.x + b4.y*b4.y + b4.z*b4.z + b4.w*b4.w;
    float ps = b4.x + b4.y + b4.z + b4.w;
    #pragma unroll
    for (int m = 1; m <= 32; m <<= 1){ p2 += __shfl_xor(p2, m); ps += __shfl_xor(ps, m); }
    if ((t & 63) == 0){ sbb[g] = p2; sbb[4+g] = ps; }
  }
  __syncthreads();
  if (t < BM){
    float* spart = &RED[0][0];
    float sx = 0.f, sh = 0.f;
    #pragma unroll
    for (int i = 0; i < 16; ++i){ sx += spart[t*16 + i]; sh += spart[256 + t*16 + i]; }
    float xn = fmaxf(sqrtf(sx), 1e-7f);
    float hn = fmaxf(sqrtf(sh), 1e-7f);
    srow[0][t] = xn; srow[1][t] = artanh_f(xn);
    srow[2][t] = hn; srow[3][t] = artanh_f(hn);
  }
  __syncthreads();

  f32x4 A[4], Bx[4];
  float bt[4], gv[4], bv[4];
  unsigned ztp[4][2];
  float hvreg[4][4];

  // ================= z gate =================
  #pragma unroll
  for (int n = 0; n < 4; ++n){
    int C = wc*64 + n*16 + lr;
    bt[n] = bias[2*HD + C]; gv[n] = gam[C]; bv[n] = bet[C];
  }
  gate_gemm(hb, wbhh + 2*65536, xb, wbih + 2*65536, A, Bx, wc, lr, lg, l);
  gate_reduce_chain(A, Bx, bt, RED, kco, srow, sbb, 2, 2, t, wc, lr, lg);
  #pragma unroll
  for (int q = 0; q < 4; ++q){
    int R = lg*4 + q;
    float KA=kco[R][0], KB=kco[R][1], Kb=kco[R][2], mu=kco[R][3], is=kco[R][4];
    #pragma unroll
    for (int n = 0; n < 4; ++n){
      float ln = (KA*A[n][q] + KB*Bx[n][q] + Kb*bt[n] - mu)*is*gv[n] + bv[n];
      unsigned zb = f2bf(sigmoid_f(ln));
      if ((q & 1) == 0) ztp[n][q>>1] = zb;
      else              ztp[n][q>>1] |= (zb << 16);
    }
  }

  // ================= r gate =================
  #pragma unroll
  for (int n = 0; n < 4; ++n){
    int C = wc*64 + n*16 + lr;
    bt[n] = bias[C]; gv[n] = gam[HD + C]; bv[n] = bet[HD + C];
  }
  gate_gemm(hb, wbhh, xb, wbih, A, Bx, wc, lr, lg, l);
  gate_reduce_chain(A, Bx, bt, RED, kco, srow, sbb, 2, 0, t, wc, lr, lg);
  // r phase3: rh_raw into Bx, stash h (bf16->f32) into hvreg, |rh|^2 partials
  {
    #pragma unroll
    for (int q = 0; q < 4; ++q){
      int R = lg*4 + q;
      float KA=kco[R][0], KB=kco[R][1], Kb=kco[R][2], mu=kco[R][3], is=kco[R][4];
      float acc = 0.f;
      #pragma unroll
      for (int n = 0; n < 4; ++n){
        int C = wc*64 + n*16 + lr;
        float hv = bf2f(hb[swz(R, C)]);
        hvreg[n][q] = hv;
        float ln = (KA*A[n][q] + KB*Bx[n][q] + Kb*bt[n] - mu)*is*gv[n] + bv[n];
        float rhv = sigmoid_f(ln) * hv;
        Bx[n][q] = rhv;
        acc = fmaf(rhv, rhv, acc);
      }
      float v2 = acc;
      v2 += __shfl_xor(v2,1); v2 += __shfl_xor(v2,2);
      v2 += __shfl_xor(v2,4); v2 += __shfl_xor(v2,8);
      if (lr == 0) RED[R][wc*8] = v2;
    }
  }
  __syncthreads();
  if (t < BM){
    int R = t;
    float s0 = RED[R][0] + RED[R][8] + RED[R][16] + RED[R][24];
    float wraw = sqrtf(s0); float wn = fmaxf(wraw, 1e-7f);
    float s = tanh_f(wn / srow[2][R] * srow[3][R]);
    float sc = (wraw <= 1e-7f) ? 0.f : s / wn;
    float rn = fmaxf((wraw <= 1e-7f) ? 0.f : fabsf(s), 1e-7f);
    kco[R][0] = sc; srow[4][R] = rn; srow[5][R] = artanh_f(rn);
  }
  __syncthreads();
  #pragma unroll
  for (int q = 0; q < 4; ++q){
    int R = lg*4 + q;
    float sc = kco[R][0];
    #pragma unroll
    for (int n = 0; n < 4; ++n){
      int C = wc*64 + n*16 + lr;
      hb[swz(R, C)] = f2bf(sc * Bx[n][q]);
    }
  }
  __syncthreads();   // rh staged before h-GEMM

  // ================= h gate =================
  #pragma unroll
  for (int n = 0; n < 4; ++n){
    int C = wc*64 + n*16 + lr;
    bt[n] = bias[HD + C]; gv[n] = gam[2*HD + C]; bv[n] = bet[2*HD + C];
  }
  gate_gemm(hb, wbhh + 65536, xb, wbih + 65536, A, Bx, wc, lr, lg, l);
  gate_reduce_chain(A, Bx, bt, RED, kco, srow, sbb, 4, 1, t, wc, lr, lg);
  // h phase3: u = tanh(ln) into A, |u|^2 partials
  {
    #pragma unroll
    for (int q = 0; q < 4; ++q){
      int R = lg*4 + q;
      float KA=kco[R][0], KB=kco[R][1], Kb=kco[R][2], mu=kco[R][3], is=kco[R][4];
      float acc = 0.f;
      #pragma unroll
      for (int n = 0; n < 4; ++n){
        float ln = (KA*A[n][q] + KB*Bx[n][q] + Kb*bt[n] - mu)*is*gv[n] + bv[n];
        float uv = tanh_f(ln);
        A[n][q] = uv;
        acc = fmaf(uv, uv, acc);
      }
      float v2 = acc;
      v2 += __shfl_xor(v2,1); v2 += __shfl_xor(v2,2);
      v2 += __shfl_xor(v2,4); v2 += __shfl_xor(v2,8);
      if (lr == 0) RED[R][wc*8] = v2;
    }
  }
  __syncthreads();
  if (t < BM){
    int R = t;
    float s0 = RED[R][0] + RED[R][8] + RED[R][16] + RED[R][24];
    float unraw = sqrtf(s0);
    float un = fmaxf(unraw, 1e-7f);
    float es = tanh_f(un) / un;
    float htn = fmaxf(es * unraw, 1e-7f);
    kco[R][0] = es; srow[6][R] = htn; srow[7][R] = artanh_f(htn);
  }
  __syncthreads();

  // ================= final combine =================
  #pragma unroll
  for (int q = 0; q < 4; ++q){
    int R = lg*4 + q;
    float es = kco[R][0];
    float a1 = 0.f, a2 = 0.f, a12 = 0.f;
    #pragma unroll
    for (int n = 0; n < 4; ++n){
      unsigned zp = ztp[n][q >> 1];
      float zv = __uint_as_float((q & 1) ? (zp & 0xFFFF0000u) : (zp << 16));
      float w2v = zv * es * A[n][q];
      float w1v = (1.f - zv) * hvreg[n][q];
      A[n][q]  = w1v;
      Bx[n][q] = w2v;
      a1 = fmaf(w1v, w1v, a1); a2 = fmaf(w2v, w2v, a2); a12 = fmaf(w1v, w2v, a12);
    }
    float v1 = a1, v2 = a2, v3 = a12;
    v1 += __shfl_xor(v1,1); v2 += __shfl_xor(v2,1); v3 += __shfl_xor(v3,1);
    v1 += __shfl_xor(v1,2); v2 += __shfl_xor(v2,2); v3 += __shfl_xor(v3,2);
    v1 += __shfl_xor(v1,4); v2 += __shfl_xor(v2,4); v3 += __shfl_xor(v3,4);
    v1 += __shfl_xor(v1,8); v2 += __shfl_xor(v2,8); v3 += __shfl_xor(v3,8);
    if (lr == 0){
      RED[R][wc*8]   = v1;
      RED[R][wc*8+1] = v2;
      RED[R][wc*8+2] = v3;
    }
  }
  __syncthreads();
  if (t < BM){
    int R = t;
    float s1  = RED[R][0] + RED[R][8]  + RED[R][16] + RED[R][24];
    float s2  = RED[R][1] + RED[R][9]  + RED[R][17] + RED[R][25];
    float s12 = RED[R][2] + RED[R][10] + RED[R][18] + RED[R][26];
    float raw1 = sqrtf(s1); float n1 = fmaxf(raw1, 1e-7f);
    float ss1 = tanh_f(n1 / srow[2][R] * srow[3][R]);
    float sc1 = (raw1 <= 1e-7f) ? 0.f : ss1 / n1;
    float t1  = (raw1 <= 1e-7f) ? 0.f : ss1*ss1;
    float raw2 = sqrtf(s2); float n2 = fmaxf(raw2, 1e-7f);
    float ss2 = tanh_f(n2 / srow[6][R] * srow[7][R]);
    float sc2 = (raw2 <= 1e-7f) ? 0.f : ss2 / n2;
    float t2  = (raw2 <= 1e-7f) ? 0.f : ss2*ss2;
    float xy = sc1*sc2*s12;
    float ca = 1.f + 2.f*xy + t2;
    float cb = 1.f - t1;
    float den = fmaxf(1.f + 2.f*xy + t1*t2, 1e-15f);
    kco[R][0] = ca*sc1/den;
    kco[R][1] = cb*sc2/den;
  }
  __syncthreads();
  #pragma unroll
  for (int q = 0; q < 4; ++q){
    int R = lg*4 + q;
    float cw1 = kco[R][0], cw2 = kco[R][1];
    #pragma unroll
    for (int n = 0; n < 4; ++n){
      int C = wc*64 + n*16 + lr;
      out[(row0 + R)*HD + C] = cw1*A[n][q] + cw2*Bx[n][q];
    }
  }
}

extern "C" void kernel_launch(void* const* d_in, const int* in_sizes, int n_in,
                              void* d_out, int out_size, void* d_ws, size_t ws_size,
                              hipStream_t stream){
  const float* x    = (const float*)d_in[0];
  const float* hx   = (const float*)d_in[1];
  const float* Wih  = (const float*)d_in[2];
  const float* Whh  = (const float*)d_in[3];
  const float* bias = (const float*)d_in[4];
  const float* gam  = (const float*)d_in[5];
  const float* bet  = (const float*)d_in[6];
  float* out = (float*)d_out;
  unsigned short* wb = (unsigned short*)d_ws;
  const int B = in_sizes[0] / HD;

  hipLaunchKernelGGL(convert_w_kernel, dim3(192), dim3(256), 0, stream, Wih, Whh, wb);
  hipLaunchKernelGGL(mobius_gru_mfma, dim3(B / BM), dim3(NTH), 0, stream,
                     x, hx, wb, wb + 3*65536, bias, gam, bet, out, B);
}

// Round 9
// 247.007 us; speedup vs baseline: 1.2063x; 1.2063x over previous
//
#include <hip/hip_runtime.h>
#include <math.h>

#define HD  256
#define BM  16
#define NTH 256

typedef __attribute__((ext_vector_type(8))) short bf16x8;
typedef __attribute__((ext_vector_type(4))) float f32x4;

__device__ __forceinline__ float rcp_f(float x){ return __builtin_amdgcn_rcpf(x); }
__device__ __forceinline__ float tanh_f(float x){
  float ax = fabsf(x);
  float e  = __expf(-2.f*ax);
  float t  = (1.f - e) * rcp_f(1.f + e);
  return copysignf(t, x);
}
__device__ __forceinline__ float artanh_f(float v){
  v = fminf(fmaxf(v, -1.f + 1e-7f), 1.f - 1e-7f);
  return 0.5f * __logf((1.f + v) * rcp_f(1.f - v));
}
__device__ __forceinline__ float sigmoid_f(float v){ return rcp_f(1.f + __expf(-v)); }
__device__ __forceinline__ unsigned short f2bf(float f){
  unsigned u = __float_as_uint(f);
  u += 0x7FFFu + ((u >> 16) & 1u);
  return (unsigned short)(u >> 16);
}
__device__ __forceinline__ float bf2f(unsigned short h){
  return __uint_as_float(((unsigned)h) << 16);
}
__device__ __forceinline__ int swz(int R, int C){
  return R*HD + (((C >> 3) ^ (R & 7)) << 3) + (C & 7);
}

// ---- W fp32 -> bf16 in MFMA-fragment order ----
__global__ void convert_w_kernel(const float* __restrict__ Wih,
                                 const float* __restrict__ Whh,
                                 unsigned short* __restrict__ wb){
  int c = blockIdx.x * blockDim.x + threadIdx.x;
  if (c >= 6 * 8192) return;
  int mat = c >> 13;
  int ci  = c & 8191;
  int l = ci & 63, st = ci >> 6;
  int s = st & 7, ct = st >> 3;
  int col = ct * 16 + (l & 15);
  int k0  = s * 32 + (l >> 4) * 8;
  const float* src = (mat < 3) ? (Wih + (size_t)mat * HD * HD)
                               : (Whh + (size_t)(mat - 3) * HD * HD);
  const float* p = src + (size_t)col * HD + k0;
  unsigned short tmp[8];
  #pragma unroll
  for (int j = 0; j < 8; ++j) tmp[j] = f2bf(p[j]);
  *(bf16x8*)(wb + (size_t)mat * 65536 + (size_t)ci * 8) = *(bf16x8*)tmp;
}

// ---- 7-value reduction for one (A,B) gate pair -> RED[R][wc*8+j], j=0..6 ----
__device__ __forceinline__ void reduce7(
    const f32x4* A, const f32x4* B, const float* bt,
    float (*RED)[33], int wc, int lr, int lg){
  float p[7][4];
  #pragma unroll
  for (int q = 0; q < 4; ++q){
    float a2=0.f,b2=0.f,ab=0.f,sA=0.f,sB=0.f,Ab=0.f,Bb=0.f;
    #pragma unroll
    for (int n = 0; n < 4; ++n){
      float ae = A[n][q], be = B[n][q], bv = bt[n];
      a2 = fmaf(ae,ae,a2); b2 = fmaf(be,be,b2); ab = fmaf(ae,be,ab);
      sA += ae; sB += be; Ab = fmaf(ae,bv,Ab); Bb = fmaf(be,bv,Bb);
    }
    p[0][q]=a2; p[1][q]=b2; p[2][q]=ab; p[3][q]=sA; p[4][q]=sB; p[5][q]=Ab; p[6][q]=Bb;
  }
  #pragma unroll
  for (int j = 0; j < 7; ++j)
    #pragma unroll
    for (int q = 0; q < 4; ++q){
      float v = p[j][q];
      v += __shfl_xor(v,1); v += __shfl_xor(v,2);
      v += __shfl_xor(v,4); v += __shfl_xor(v,8);
      p[j][q] = v;
    }
  if (lr == 0){
    #pragma unroll
    for (int q = 0; q < 4; ++q){
      int R = lg*4 + q;
      #pragma unroll
      for (int j = 0; j < 7; ++j) RED[R][wc*8 + j] = p[j][q];
    }
  }
}

// ---- once-per-row mobius+LN chain: s[7] -> {KA,KB,Kb,mu,is} ----
__device__ __forceinline__ void chain5(
    const float* s, float bb, float sbs,
    float an, float aa, float bn, float ba, float* o){
  float mraw = sqrtf(s[0]); float mA = fmaxf(mraw, 1e-7f);
  float tA = tanh_f(mA / an * aa);
  float sa  = (mraw <= 1e-7f) ? 0.f : tA / mA;
  float x2a = (mraw <= 1e-7f) ? 0.f : tA*tA;
  float nraw = sqrtf(s[1]); float mB = fmaxf(nraw, 1e-7f);
  float tB = tanh_f(mB / bn * ba);
  float sb_ = (nraw <= 1e-7f) ? 0.f : tB / mB;
  float x2b = (nraw <= 1e-7f) ? 0.f : tB*tB;
  float xy = sa*sb_*s[2];
  float ca = 1.f + 2.f*xy + x2b;
  float cb = 1.f - x2a;
  float den = fmaxf(1.f + 2.f*xy + x2a*x2b, 1e-15f);
  float u = ca*sa/den, v = cb*sb_/den;
  float P2 = u*u*s[0] + 2.f*u*v*s[2] + v*v*s[1];
  float Pb = u*s[5] + v*s[6];
  float sP = u*s[3] + v*s[4];
  float ca2 = 1.f + 2.f*Pb + bb;
  float cb2 = 1.f - P2;
  float den2 = fmaxf(1.f + 2.f*Pb + P2*bb, 1e-15f);
  float pp = ca2/den2, ww = cb2/den2;
  float Q2 = pp*pp*P2 + 2.f*pp*ww*Pb + ww*ww*bb;
  float sQsum = pp*sP + ww*sbs;
  float qn = fmaxf(sqrtf(Q2), 1e-7f);
  float sQ = artanh_f(qn) / qn;
  float mu = sQ*sQsum*(1.f/HD);
  float e2 = sQ*sQ*Q2*(1.f/HD);
  float is = rsqrtf(e2 - mu*mu + 1e-5f);
  o[0] = sQ*pp*u;  o[1] = sQ*pp*v;  o[2] = sQ*ww;
  o[3] = mu;       o[4] = is;
}

// R5 (fused 5-stream GEMM, best at 219us) + per-lane redundant chains:
// every serial t<16/t<32 chain section is replaced by all-lane computation
// (lane handles row lg*4+(lr&3); z/r pair split lr<8 / lr>=8) with __shfl
// redistribution from lane (l&48)+q. Deletes 5 barriers (13 -> 8) and all
// 1/8-utilization serial sections. Mini-chain partials use RED col 7 of
// each 8-col slot so chain reads (cols 0-6) never race partial writes.
// Proven (256,2) tier: ~193 live regs <= 256 budget, no spill.
__global__ __launch_bounds__(NTH, 2) void mobius_gru_mfma(
    const float* __restrict__ x, const float* __restrict__ hx,
    const unsigned short* __restrict__ wbih, const unsigned short* __restrict__ wbhh,
    const float* __restrict__ bias, const float* __restrict__ gam,
    const float* __restrict__ bet, float* __restrict__ out, int B){
  __shared__ unsigned short xb[BM*HD];
  __shared__ unsigned short hb[BM*HD];
  __shared__ float REDZ[BM][33];
  __shared__ float REDR[BM][33];
  __shared__ float srow[8][BM];   // 0:xn 1:xa 2:hn 3:ha 4:rn 5:ra 6:htn 7:hta
  __shared__ float sbb[8];        // [g]=sum b^2, [4+g]=sum b

  const int t  = threadIdx.x;
  const int l  = t & 63;
  const int lr = l & 15, lg = l >> 4;
  const int wc = t >> 6;          // 4 waves, one 64-col slice each
  const int crow = lg*4 + (lr & 3);   // per-lane chain row
  const size_t row0 = (size_t)blockIdx.x * BM;

  // ---- stage x,hx -> bf16 swizzled LDS + norm partials (spart overlays REDZ) ----
  {
    float* spart = &REDZ[0][0];   // [0,256): x partials, [256,512): h partials
    int r = t >> 4, seg = t & 15;
    const float* xp = x  + (row0 + r)*HD + seg*16;
    const float* hp = hx + (row0 + r)*HD + seg*16;
    float sx = 0.f, sh = 0.f;
    #pragma unroll
    for (int i = 0; i < 4; ++i){
      int c = seg*16 + i*4;
      int di = swz(r, c);
      float4 v = *(const float4*)(xp + i*4);
      sx += v.x*v.x + v.y*v.y + v.z*v.z + v.w*v.w;
      ushort4 o = { f2bf(v.x), f2bf(v.y), f2bf(v.z), f2bf(v.w) };
      *(ushort4*)&xb[di] = o;
      v = *(const float4*)(hp + i*4);
      sh += v.x*v.x + v.y*v.y + v.z*v.z + v.w*v.w;
      ushort4 o2 = { f2bf(v.x), f2bf(v.y), f2bf(v.z), f2bf(v.w) };
      *(ushort4*)&hb[di] = o2;
    }
    spart[r*16 + seg] = sx; spart[256 + r*16 + seg] = sh;
  }
  if (t >= 64 && t < 256){
    int g = (t >> 6) - 1;
    float4 b4 = *(const float4*)&bias[g*HD + (t & 63)*4];
    float p2 = b4.x*b4.x + b4.y*b4.y + b4.z*b4.z + b4.w*b4.w;
    float ps = b4.x + b4.y + b4.z + b4.w;
    #pragma unroll
    for (int m = 1; m <= 32; m <<= 1){ p2 += __shfl_xor(p2, m); ps += __shfl_xor(ps, m); }
    if ((t & 63) == 0){ sbb[g] = p2; sbb[4+g] = ps; }
  }
  __syncthreads();
  if (t < 32){
    float* spart = &REDZ[0][0];
    int R = t & 15, sel = t >> 4;     // sel 0: x, 1: h
    const float* base = spart + sel*256;
    float sv = 0.f;
    #pragma unroll
    for (int i = 0; i < 16; ++i) sv += base[R*16 + i];
    float nn = fmaxf(sqrtf(sv), 1e-7f);
    srow[sel*2][R] = nn; srow[sel*2+1][R] = artanh_f(nn);
  }
  __syncthreads();

  // ================= fused z + r + x-of-h GEMM (5 weight streams) =========
  f32x4 Az[4], Bz[4], Ar[4], Br[4], Bh[4];
  float btz[4], btr[4];
  #pragma unroll
  for (int n = 0; n < 4; ++n){
    int C = wc*64 + n*16 + lr;
    btz[n] = bias[2*HD + C];
    btr[n] = bias[C];
    Az[n] = (f32x4){0.f,0.f,0.f,0.f}; Bz[n] = (f32x4){0.f,0.f,0.f,0.f};
    Ar[n] = (f32x4){0.f,0.f,0.f,0.f}; Br[n] = (f32x4){0.f,0.f,0.f,0.f};
    Bh[n] = (f32x4){0.f,0.f,0.f,0.f};
  }
  {
    const unsigned short* wHz = wbhh + 2*65536;
    const unsigned short* wXz = wbih + 2*65536;
    const unsigned short* wHr = wbhh;
    const unsigned short* wXr = wbih;
    const unsigned short* wXh = wbih + 65536;
    #pragma unroll
    for (int s = 0; s < 8; ++s){
      int idx = lr*HD + (((4*s + lg) ^ (lr & 7)) << 3);
      bf16x8 ah = *(const bf16x8*)&hb[idx];
      bf16x8 ax = *(const bf16x8*)&xb[idx];
      #pragma unroll
      for (int n = 0; n < 4; ++n){
        int off = (((wc*4 + n)*8 + s)*64 + l)*8;
        bf16x8 bhz = *(const bf16x8*)(wHz + off);
        bf16x8 bxz = *(const bf16x8*)(wXz + off);
        bf16x8 bhr = *(const bf16x8*)(wHr + off);
        bf16x8 bxr = *(const bf16x8*)(wXr + off);
        bf16x8 bxh = *(const bf16x8*)(wXh + off);
        Az[n] = __builtin_amdgcn_mfma_f32_16x16x32_bf16(ah, bhz, Az[n], 0, 0, 0);
        Bz[n] = __builtin_amdgcn_mfma_f32_16x16x32_bf16(ax, bxz, Bz[n], 0, 0, 0);
        Ar[n] = __builtin_amdgcn_mfma_f32_16x16x32_bf16(ah, bhr, Ar[n], 0, 0, 0);
        Br[n] = __builtin_amdgcn_mfma_f32_16x16x32_bf16(ax, bxr, Br[n], 0, 0, 0);
        Bh[n] = __builtin_amdgcn_mfma_f32_16x16x32_bf16(ax, bxh, Bh[n], 0, 0, 0);
      }
    }
  }
  reduce7(Az, Bz, btz, REDZ, wc, lr, lg);
  reduce7(Ar, Br, btr, REDR, wc, lr, lg);
  __syncthreads();                                   // bar1

  // ---- per-lane chain z (lr<8) / r (lr>=8), then shuffle-distribute ----
  float KAz[4],KBz[4],Kbz[4],muz[4],isz[4];
  float KAr[4],KBr[4],Kbr[4],mur[4],ISr[4];
  {
    bool doR = (lr >= 8);
    float (*REDp)[33] = doR ? REDR : REDZ;
    int gidx = doR ? 0 : 2;
    float s[7];
    #pragma unroll
    for (int j = 0; j < 7; ++j)
      s[j] = REDp[crow][j] + REDp[crow][8+j] + REDp[crow][16+j] + REDp[crow][24+j];
    float o[5];
    chain5(s, sbb[gidx], sbb[4+gidx],
           srow[2][crow], srow[3][crow], srow[0][crow], srow[1][crow], o);
    #pragma unroll
    for (int q = 0; q < 4; ++q){
      int zs = (l & 48) + q, rs = zs + 8;
      KAz[q]=__shfl(o[0],zs); KBz[q]=__shfl(o[1],zs); Kbz[q]=__shfl(o[2],zs);
      muz[q]=__shfl(o[3],zs); isz[q]=__shfl(o[4],zs);
      KAr[q]=__shfl(o[0],rs); KBr[q]=__shfl(o[1],rs); Kbr[q]=__shfl(o[2],rs);
      mur[q]=__shfl(o[3],rs); ISr[q]=__shfl(o[4],rs);
    }
  }

  // ---- fused z/r phase3: ztp pack, rh_raw into Br, h stash, |rh|^2 -> col 7
  unsigned ztp[4][2];
  float hvreg[4][4];
  {
    float gvz[4], bvz[4], gvr[4], bvr[4];
    #pragma unroll
    for (int n = 0; n < 4; ++n){
      int C = wc*64 + n*16 + lr;
      gvz[n] = gam[C];      bvz[n] = bet[C];
      gvr[n] = gam[HD + C]; bvr[n] = bet[HD + C];
    }
    #pragma unroll
    for (int q = 0; q < 4; ++q){
      int R = lg*4 + q;
      float acc = 0.f;
      #pragma unroll
      for (int n = 0; n < 4; ++n){
        int C = wc*64 + n*16 + lr;
        float hv = bf2f(hb[swz(R, C)]);
        hvreg[n][q] = hv;
        float lnz = (KAz[q]*Az[n][q] + KBz[q]*Bz[n][q] + Kbz[q]*btz[n] - muz[q])*isz[q]*gvz[n] + bvz[n];
        unsigned zb = f2bf(sigmoid_f(lnz));
        if ((q & 1) == 0) ztp[n][q>>1] = zb;
        else              ztp[n][q>>1] |= (zb << 16);
        float lnr = (KAr[q]*Ar[n][q] + KBr[q]*Br[n][q] + Kbr[q]*btr[n] - mur[q])*ISr[q]*gvr[n] + bvr[n];
        float rhv = sigmoid_f(lnr) * hv;
        Br[n][q] = rhv;
        acc = fmaf(rhv, rhv, acc);
      }
      float v2 = acc;
      v2 += __shfl_xor(v2,1); v2 += __shfl_xor(v2,2);
      v2 += __shfl_xor(v2,4); v2 += __shfl_xor(v2,8);
      if (lr == 0) REDZ[R][wc*8 + 7] = v2;
    }
  }
  __syncthreads();                                   // bar2

  // ---- per-lane r2 mini-chain (reads col 7s), shuffle sc ----
  float scq[4];
  {
    float s0 = REDZ[crow][7] + REDZ[crow][15] + REDZ[crow][23] + REDZ[crow][31];
    float wraw = sqrtf(s0); float wn = fmaxf(wraw, 1e-7f);
    float sv = tanh_f(wn / srow[2][crow] * srow[3][crow]);
    float sc = (wraw <= 1e-7f) ? 0.f : sv / wn;
    float rn = fmaxf((wraw <= 1e-7f) ? 0.f : fabsf(sv), 1e-7f);
    if (wc == 0 && lr < 4){ srow[4][crow] = rn; srow[5][crow] = artanh_f(rn); }
    #pragma unroll
    for (int q = 0; q < 4; ++q) scq[q] = __shfl(sc, (l & 48) + q);
  }
  // rh scale + store (h already stashed in hvreg)
  #pragma unroll
  for (int q = 0; q < 4; ++q){
    int R = lg*4 + q;
    #pragma unroll
    for (int n = 0; n < 4; ++n){
      int C = wc*64 + n*16 + lr;
      hb[swz(R, C)] = f2bf(scq[q] * Br[n][q]);
    }
  }
  __syncthreads();                                   // bar3 (rh staged)

  // ================= h gate: single-stream GEMM (x-side prefused in Bh) ====
  f32x4 Ah[4];
  float bth[4];
  #pragma unroll
  for (int n = 0; n < 4; ++n){
    int C = wc*64 + n*16 + lr;
    bth[n] = bias[HD + C];
    Ah[n] = (f32x4){0.f,0.f,0.f,0.f};
  }
  {
    const unsigned short* wHh = wbhh + 65536;
    #pragma unroll
    for (int s = 0; s < 8; ++s){
      int idx = lr*HD + (((4*s + lg) ^ (lr & 7)) << 3);
      bf16x8 ar = *(const bf16x8*)&hb[idx];
      #pragma unroll
      for (int n = 0; n < 4; ++n){
        int off = (((wc*4 + n)*8 + s)*64 + l)*8;
        bf16x8 bh = *(const bf16x8*)(wHh + off);
        Ah[n] = __builtin_amdgcn_mfma_f32_16x16x32_bf16(ar, bh, Ah[n], 0, 0, 0);
      }
    }
  }
  reduce7(Ah, Bh, bth, REDZ, wc, lr, lg);
  __syncthreads();                                   // bar4

  // ---- per-lane h-chain, shuffle-distribute ----
  float KA[4],KB[4],Kb[4],MU[4],IS[4];
  {
    float s[7];
    #pragma unroll
    for (int j = 0; j < 7; ++j)
      s[j] = REDZ[crow][j] + REDZ[crow][8+j] + REDZ[crow][16+j] + REDZ[crow][24+j];
    float o[5];
    chain5(s, sbb[1], sbb[5],
           srow[4][crow], srow[5][crow], srow[0][crow], srow[1][crow], o);
    #pragma unroll
    for (int q = 0; q < 4; ++q){
      int src = (l & 48) + q;
      KA[q]=__shfl(o[0],src); KB[q]=__shfl(o[1],src); Kb[q]=__shfl(o[2],src);
      MU[q]=__shfl(o[3],src); IS[q]=__shfl(o[4],src);
    }
  }
  // h phase3: u = tanh(ln) into Ah, |u|^2 -> col 7
  {
    float gvh[4], bvh[4];
    #pragma unroll
    for (int n = 0; n < 4; ++n){
      int C = wc*64 + n*16 + lr;
      gvh[n] = gam[2*HD + C]; bvh[n] = bet[2*HD + C];
    }
    #pragma unroll
    for (int q = 0; q < 4; ++q){
      int R = lg*4 + q;
      float acc = 0.f;
      #pragma unroll
      for (int n = 0; n < 4; ++n){
        float ln = (KA[q]*Ah[n][q] + KB[q]*Bh[n][q] + Kb[q]*bth[n] - MU[q])*IS[q]*gvh[n] + bvh[n];
        float uv = tanh_f(ln);
        Ah[n][q] = uv;
        acc = fmaf(uv, uv, acc);
      }
      float v2 = acc;
      v2 += __shfl_xor(v2,1); v2 += __shfl_xor(v2,2);
      v2 += __shfl_xor(v2,4); v2 += __shfl_xor(v2,8);
      if (lr == 0) REDZ[R][wc*8 + 7] = v2;
    }
  }
  __syncthreads();                                   // bar5

  // ---- per-lane h2 mini-chain (col 7s), shuffle es ----
  float esq[4];
  {
    float s0 = REDZ[crow][7] + REDZ[crow][15] + REDZ[crow][23] + REDZ[crow][31];
    float unraw = sqrtf(s0);
    float un = fmaxf(unraw, 1e-7f);
    float es = tanh_f(un) / un;
    float htn = fmaxf(es * unraw, 1e-7f);
    if (wc == 0 && lr < 4){ srow[6][crow] = htn; srow[7][crow] = artanh_f(htn); }
    #pragma unroll
    for (int q = 0; q < 4; ++q) esq[q] = __shfl(es, (l & 48) + q);
  }

  // ================= final combine =================
  #pragma unroll
  for (int q = 0; q < 4; ++q){
    int R = lg*4 + q;
    float a1 = 0.f, a2 = 0.f, a12 = 0.f;
    #pragma unroll
    for (int n = 0; n < 4; ++n){
      unsigned zp = ztp[n][q >> 1];
      float zv = __uint_as_float((q & 1) ? (zp & 0xFFFF0000u) : (zp << 16));
      float w2v = zv * esq[q] * Ah[n][q];
      float w1v = (1.f - zv) * hvreg[n][q];
      Ah[n][q] = w2v;
      Bh[n][q] = w1v;
      a1 = fmaf(w1v, w1v, a1); a2 = fmaf(w2v, w2v, a2); a12 = fmaf(w1v, w2v, a12);
    }
    float v1 = a1, v2 = a2, v3 = a12;
    v1 += __shfl_xor(v1,1); v2 += __shfl_xor(v2,1); v3 += __shfl_xor(v3,1);
    v1 += __shfl_xor(v1,2); v2 += __shfl_xor(v2,2); v3 += __shfl_xor(v3,2);
    v1 += __shfl_xor(v1,4); v2 += __shfl_xor(v2,4); v3 += __shfl_xor(v3,4);
    v1 += __shfl_xor(v1,8); v2 += __shfl_xor(v2,8); v3 += __shfl_xor(v3,8);
    if (lr == 0){
      REDZ[R][wc*8]   = v1;
      REDZ[R][wc*8+1] = v2;
      REDZ[R][wc*8+2] = v3;
    }
  }
  __syncthreads();                                   // bar6

  // ---- per-lane final chain, shuffle cw1/cw2 ----
  float cw1q[4], cw2q[4];
  {
    float s1  = REDZ[crow][0] + REDZ[crow][8]  + REDZ[crow][16] + REDZ[crow][24];
    float s2  = REDZ[crow][1] + REDZ[crow][9]  + REDZ[crow][17] + REDZ[crow][25];
    float s12 = REDZ[crow][2] + REDZ[crow][10] + REDZ[crow][18] + REDZ[crow][26];
    float raw1 = sqrtf(s1); float n1 = fmaxf(raw1, 1e-7f);
    float ss1 = tanh_f(n1 / srow[2][crow] * srow[3][crow]);
    float sc1 = (raw1 <= 1e-7f) ? 0.f : ss1 / n1;
    float t1  = (raw1 <= 1e-7f) ? 0.f : ss1*ss1;
    float raw2 = sqrtf(s2); float n2 = fmaxf(raw2, 1e-7f);
    float ss2 = tanh_f(n2 / srow[6][crow] * srow[7][crow]);
    float sc2 = (raw2 <= 1e-7f) ? 0.f : ss2 / n2;
    float t2  = (raw2 <= 1e-7f) ? 0.f : ss2*ss2;
    float xy = sc1*sc2*s12;
    float ca = 1.f + 2.f*xy + t2;
    float cb = 1.f - t1;
    float den = fmaxf(1.f + 2.f*xy + t1*t2, 1e-15f);
    float cw1 = ca*sc1/den;
    float cw2 = cb*sc2/den;
    #pragma unroll
    for (int q = 0; q < 4; ++q){
      int src = (l & 48) + q;
      cw1q[q] = __shfl(cw1, src);
      cw2q[q] = __shfl(cw2, src);
    }
  }
  #pragma unroll
  for (int q = 0; q < 4; ++q){
    int R = lg*4 + q;
    #pragma unroll
    for (int n = 0; n < 4; ++n){
      int C = wc*64 + n*16 + lr;
      out[(row0 + R)*HD + C] = cw1q[q]*Bh[n][q] + cw2q[q]*Ah[n][q];
    }
  }
}

extern "C" void kernel_launch(void* const* d_in, const int* in_sizes, int n_in,
                              void* d_out, int out_size, void* d_ws, size_t ws_size,
                              hipStream_t stream){
  const float* x    = (const float*)d_in[0];
  const float* hx   = (const float*)d_in[1];
  const float* Wih  = (const float*)d_in[2];
  const float* Whh  = (const float*)d_in[3];
  const float* bias = (const float*)d_in[4];
  const float* gam  = (const float*)d_in[5];
  const float* bet  = (const float*)d_in[6];
  float* out = (float*)d_out;
  unsigned short* wb = (unsigned short*)d_ws;
  const int B = in_sizes[0] / HD;

  hipLaunchKernelGGL(convert_w_kernel, dim3(192), dim3(256), 0, stream, Wih, Whh, wb);
  hipLaunchKernelGGL(mobius_gru_mfma, dim3(B / BM), dim3(NTH), 0, stream,
                     x, hx, wb, wb + 3*65536, bias, gam, bet, out, B);
}

// Round 10
// 218.061 us; speedup vs baseline: 1.3664x; 1.1327x over previous
//
#include <hip/hip_runtime.h>
#include <math.h>

#define HD  256
#define BM  16
#define NTH 256

typedef __attribute__((ext_vector_type(8))) short bf16x8;
typedef __attribute__((ext_vector_type(4))) float f32x4;

__device__ __forceinline__ float rcp_f(float x){ return __builtin_amdgcn_rcpf(x); }
__device__ __forceinline__ float tanh_f(float x){
  float ax = fabsf(x);
  float e  = __expf(-2.f*ax);
  float t  = (1.f - e) * rcp_f(1.f + e);
  return copysignf(t, x);
}
__device__ __forceinline__ float artanh_f(float v){
  v = fminf(fmaxf(v, -1.f + 1e-7f), 1.f - 1e-7f);
  return 0.5f * __logf((1.f + v) * rcp_f(1.f - v));
}
__device__ __forceinline__ float sigmoid_f(float v){ return rcp_f(1.f + __expf(-v)); }
__device__ __forceinline__ unsigned short f2bf(float f){
  unsigned u = __float_as_uint(f);
  u += 0x7FFFu + ((u >> 16) & 1u);
  return (unsigned short)(u >> 16);
}
__device__ __forceinline__ float bf2f(unsigned short h){
  return __uint_as_float(((unsigned)h) << 16);
}
__device__ __forceinline__ int swz(int R, int C){
  return R*HD + (((C >> 3) ^ (R & 7)) << 3) + (C & 7);
}

// ---- W fp32 -> bf16 in MFMA-fragment order ----
__global__ void convert_w_kernel(const float* __restrict__ Wih,
                                 const float* __restrict__ Whh,
                                 unsigned short* __restrict__ wb){
  int c = blockIdx.x * blockDim.x + threadIdx.x;
  if (c >= 6 * 8192) return;
  int mat = c >> 13;
  int ci  = c & 8191;
  int l = ci & 63, st = ci >> 6;
  int s = st & 7, ct = st >> 3;
  int col = ct * 16 + (l & 15);
  int k0  = s * 32 + (l >> 4) * 8;
  const float* src = (mat < 3) ? (Wih + (size_t)mat * HD * HD)
                               : (Whh + (size_t)(mat - 3) * HD * HD);
  const float* p = src + (size_t)col * HD + k0;
  unsigned short tmp[8];
  #pragma unroll
  for (int j = 0; j < 8; ++j) tmp[j] = f2bf(p[j]);
  *(bf16x8*)(wb + (size_t)mat * 65536 + (size_t)ci * 8) = *(bf16x8*)tmp;
}

// ---- 7-value reduction for one (A,B) gate pair -> RED[R][wc*8+j], j=0..6 ----
__device__ __forceinline__ void reduce7(
    const f32x4* A, const f32x4* B, const float* bt,
    float (*RED)[33], int wc, int lr, int lg){
  float p[7][4];
  #pragma unroll
  for (int q = 0; q < 4; ++q){
    float a2=0.f,b2=0.f,ab=0.f,sA=0.f,sB=0.f,Ab=0.f,Bb=0.f;
    #pragma unroll
    for (int n = 0; n < 4; ++n){
      float ae = A[n][q], be = B[n][q], bv = bt[n];
      a2 = fmaf(ae,ae,a2); b2 = fmaf(be,be,b2); ab = fmaf(ae,be,ab);
      sA += ae; sB += be; Ab = fmaf(ae,bv,Ab); Bb = fmaf(be,bv,Bb);
    }
    p[0][q]=a2; p[1][q]=b2; p[2][q]=ab; p[3][q]=sA; p[4][q]=sB; p[5][q]=Ab; p[6][q]=Bb;
  }
  #pragma unroll
  for (int j = 0; j < 7; ++j)
    #pragma unroll
    for (int q = 0; q < 4; ++q){
      float v = p[j][q];
      v += __shfl_xor(v,1); v += __shfl_xor(v,2);
      v += __shfl_xor(v,4); v += __shfl_xor(v,8);
      p[j][q] = v;
    }
  if (lr == 0){
    #pragma unroll
    for (int q = 0; q < 4; ++q){
      int R = lg*4 + q;
      #pragma unroll
      for (int j = 0; j < 7; ++j) RED[R][wc*8 + j] = p[j][q];
    }
  }
}

// ---- once-per-row mobius+LN chain: s[7] -> {KA,KB,Kb,mu,is} ----
__device__ __forceinline__ void chain5(
    const float* s, float bb, float sbs,
    float an, float aa, float bn, float ba, float* o){
  float mraw = sqrtf(s[0]); float mA = fmaxf(mraw, 1e-7f);
  float tA = tanh_f(mA / an * aa);
  float sa  = (mraw <= 1e-7f) ? 0.f : tA / mA;
  float x2a = (mraw <= 1e-7f) ? 0.f : tA*tA;
  float nraw = sqrtf(s[1]); float mB = fmaxf(nraw, 1e-7f);
  float tB = tanh_f(mB / bn * ba);
  float sb_ = (nraw <= 1e-7f) ? 0.f : tB / mB;
  float x2b = (nraw <= 1e-7f) ? 0.f : tB*tB;
  float xy = sa*sb_*s[2];
  float ca = 1.f + 2.f*xy + x2b;
  float cb = 1.f - x2a;
  float den = fmaxf(1.f + 2.f*xy + x2a*x2b, 1e-15f);
  float u = ca*sa/den, v = cb*sb_/den;
  float P2 = u*u*s[0] + 2.f*u*v*s[2] + v*v*s[1];
  float Pb = u*s[5] + v*s[6];
  float sP = u*s[3] + v*s[4];
  float ca2 = 1.f + 2.f*Pb + bb;
  float cb2 = 1.f - P2;
  float den2 = fmaxf(1.f + 2.f*Pb + P2*bb, 1e-15f);
  float pp = ca2/den2, ww = cb2/den2;
  float Q2 = pp*pp*P2 + 2.f*pp*ww*Pb + ww*ww*bb;
  float sQsum = pp*sP + ww*sbs;
  float qn = fmaxf(sqrtf(Q2), 1e-7f);
  float sQ = artanh_f(qn) / qn;
  float mu = sQ*sQsum*(1.f/HD);
  float e2 = sQ*sQ*Q2*(1.f/HD);
  float is = rsqrtf(e2 - mu*mu + 1e-5f);
  o[0] = sQ*pp*u;  o[1] = sQ*pp*v;  o[2] = sQ*ww;
  o[3] = mu;       o[4] = is;
}

// R5 (best: 219us bench) + rh barrier fusion: phase3 writes UNSCALED rh
// in-place into hb (owner-thread read-then-write, no cross-thread hazard),
// |rh|^2 partials go to RED col 7 (reduce7 uses 0-6 -> no race), and the
// mobius row-scale is folded into Ah AFTER the h-GEMM (row scaling commutes
// with W*v, proven R6). The short r2 mini-chain runs all-lane redundant
// (~6 regs, unlike R9's big-chain blowup) off the critical path. Deletes
// 2 barriers + serial section + a full 4096-cell LDS rescale pass.
// Everything else identical to R5. (256,2) tier, ~112 regs, no spill.
__global__ __launch_bounds__(NTH, 2) void mobius_gru_mfma(
    const float* __restrict__ x, const float* __restrict__ hx,
    const unsigned short* __restrict__ wbih, const unsigned short* __restrict__ wbhh,
    const float* __restrict__ bias, const float* __restrict__ gam,
    const float* __restrict__ bet, float* __restrict__ out, int B){
  __shared__ unsigned short xb[BM*HD];
  __shared__ unsigned short hb[BM*HD];
  __shared__ float REDZ[BM][33];
  __shared__ float REDR[BM][33];
  __shared__ float kco[BM][10];   // z: 0..4, r: 5..9 (h reuses 0..4)
  __shared__ float srow[8][BM];   // 0:xn 1:xa 2:hn 3:ha 4:rn 5:ra 6:htn 7:hta
  __shared__ float sbb[8];        // [g]=sum b^2, [4+g]=sum b

  const int t  = threadIdx.x;
  const int l  = t & 63;
  const int lr = l & 15, lg = l >> 4;
  const int wc = t >> 6;          // 4 waves, one 64-col slice each
  const size_t row0 = (size_t)blockIdx.x * BM;

  // ---- stage x,hx -> bf16 swizzled LDS + norm partials (spart overlays REDZ) ----
  {
    float* spart = &REDZ[0][0];   // [0,256): x partials, [256,512): h partials
    int r = t >> 4, seg = t & 15;
    const float* xp = x  + (row0 + r)*HD + seg*16;
    const float* hp = hx + (row0 + r)*HD + seg*16;
    float sx = 0.f, sh = 0.f;
    #pragma unroll
    for (int i = 0; i < 4; ++i){
      int c = seg*16 + i*4;
      int di = swz(r, c);
      float4 v = *(const float4*)(xp + i*4);
      sx += v.x*v.x + v.y*v.y + v.z*v.z + v.w*v.w;
      ushort4 o = { f2bf(v.x), f2bf(v.y), f2bf(v.z), f2bf(v.w) };
      *(ushort4*)&xb[di] = o;
      v = *(const float4*)(hp + i*4);
      sh += v.x*v.x + v.y*v.y + v.z*v.z + v.w*v.w;
      ushort4 o2 = { f2bf(v.x), f2bf(v.y), f2bf(v.z), f2bf(v.w) };
      *(ushort4*)&hb[di] = o2;
    }
    spart[r*16 + seg] = sx; spart[256 + r*16 + seg] = sh;
  }
  if (t >= 64 && t < 256){
    int g = (t >> 6) - 1;
    float4 b4 = *(const float4*)&bias[g*HD + (t & 63)*4];
    float p2 = b4.x*b4.x + b4.y*b4.y + b4.z*b4.z + b4.w*b4.w;
    float ps = b4.x + b4.y + b4.z + b4.w;
    #pragma unroll
    for (int m = 1; m <= 32; m <<= 1){ p2 += __shfl_xor(p2, m); ps += __shfl_xor(ps, m); }
    if ((t & 63) == 0){ sbb[g] = p2; sbb[4+g] = ps; }
  }
  __syncthreads();
  if (t < BM){
    float* spart = &REDZ[0][0];
    float sx = 0.f, sh = 0.f;
    #pragma unroll
    for (int i = 0; i < 16; ++i){ sx += spart[t*16 + i]; sh += spart[256 + t*16 + i]; }
    float xn = fmaxf(sqrtf(sx), 1e-7f);
    float hn = fmaxf(sqrtf(sh), 1e-7f);
    srow[0][t] = xn; srow[1][t] = artanh_f(xn);
    srow[2][t] = hn; srow[3][t] = artanh_f(hn);
  }
  __syncthreads();

  // ================= fused z + r + x-of-h GEMM (5 weight streams) =========
  f32x4 Az[4], Bz[4], Ar[4], Br[4], Bh[4];
  float btz[4], btr[4];
  #pragma unroll
  for (int n = 0; n < 4; ++n){
    int C = wc*64 + n*16 + lr;
    btz[n] = bias[2*HD + C];
    btr[n] = bias[C];
    Az[n] = (f32x4){0.f,0.f,0.f,0.f}; Bz[n] = (f32x4){0.f,0.f,0.f,0.f};
    Ar[n] = (f32x4){0.f,0.f,0.f,0.f}; Br[n] = (f32x4){0.f,0.f,0.f,0.f};
    Bh[n] = (f32x4){0.f,0.f,0.f,0.f};
  }
  {
    const unsigned short* wHz = wbhh + 2*65536;
    const unsigned short* wXz = wbih + 2*65536;
    const unsigned short* wHr = wbhh;
    const unsigned short* wXr = wbih;
    const unsigned short* wXh = wbih + 65536;
    #pragma unroll
    for (int s = 0; s < 8; ++s){
      int idx = lr*HD + (((4*s + lg) ^ (lr & 7)) << 3);
      bf16x8 ah = *(const bf16x8*)&hb[idx];
      bf16x8 ax = *(const bf16x8*)&xb[idx];
      #pragma unroll
      for (int n = 0; n < 4; ++n){
        int off = (((wc*4 + n)*8 + s)*64 + l)*8;
        bf16x8 bhz = *(const bf16x8*)(wHz + off);
        bf16x8 bxz = *(const bf16x8*)(wXz + off);
        bf16x8 bhr = *(const bf16x8*)(wHr + off);
        bf16x8 bxr = *(const bf16x8*)(wXr + off);
        bf16x8 bxh = *(const bf16x8*)(wXh + off);
        Az[n] = __builtin_amdgcn_mfma_f32_16x16x32_bf16(ah, bhz, Az[n], 0, 0, 0);
        Bz[n] = __builtin_amdgcn_mfma_f32_16x16x32_bf16(ax, bxz, Bz[n], 0, 0, 0);
        Ar[n] = __builtin_amdgcn_mfma_f32_16x16x32_bf16(ah, bhr, Ar[n], 0, 0, 0);
        Br[n] = __builtin_amdgcn_mfma_f32_16x16x32_bf16(ax, bxr, Br[n], 0, 0, 0);
        Bh[n] = __builtin_amdgcn_mfma_f32_16x16x32_bf16(ax, bxh, Bh[n], 0, 0, 0);
      }
    }
  }
  reduce7(Az, Bz, btz, REDZ, wc, lr, lg);
  reduce7(Ar, Br, btr, REDR, wc, lr, lg);
  __syncthreads();
  // z chain on t<16, r chain on 16<=t<32 — same code path, disjoint threads
  if (t < 32){
    int R = t & 15, gsel = t >> 4;            // 0: z (gidx 2), 1: r (gidx 0)
    float (*REDp)[33] = gsel ? REDR : REDZ;
    int gidx = gsel ? 0 : 2;
    float s[7];
    #pragma unroll
    for (int j = 0; j < 7; ++j)
      s[j] = REDp[R][j] + REDp[R][8+j] + REDp[R][16+j] + REDp[R][24+j];
    float o[5];
    chain5(s, sbb[gidx], sbb[4+gidx],
           srow[2][R], srow[3][R], srow[0][R], srow[1][R], o);
    #pragma unroll
    for (int k = 0; k < 5; ++k) kco[R][gsel*5 + k] = o[k];
  }
  __syncthreads();

  // ---- fused z/r phase3: ztp pack, UNSCALED rh in-place into hb, h stash,
  //      |rh|^2 partials -> RED col 7 (reduce7 writes only cols 0-6)
  unsigned ztp[4][2];
  float hvreg[4][4];
  {
    float gvz[4], bvz[4], gvr[4], bvr[4];
    #pragma unroll
    for (int n = 0; n < 4; ++n){
      int C = wc*64 + n*16 + lr;
      gvz[n] = gam[C];      bvz[n] = bet[C];
      gvr[n] = gam[HD + C]; bvr[n] = bet[HD + C];
    }
    #pragma unroll
    for (int q = 0; q < 4; ++q){
      int R = lg*4 + q;
      float KAz=kco[R][0], KBz=kco[R][1], Kbz=kco[R][2], muz=kco[R][3], isz=kco[R][4];
      float KAr=kco[R][5], KBr=kco[R][6], Kbr=kco[R][7], mur=kco[R][8], isr=kco[R][9];
      float acc = 0.f;
      #pragma unroll
      for (int n = 0; n < 4; ++n){
        int C = wc*64 + n*16 + lr;
        float hv = bf2f(hb[swz(R, C)]);
        hvreg[n][q] = hv;
        float lnz = (KAz*Az[n][q] + KBz*Bz[n][q] + Kbz*btz[n] - muz)*isz*gvz[n] + bvz[n];
        unsigned zb = f2bf(sigmoid_f(lnz));
        if ((q & 1) == 0) ztp[n][q>>1] = zb;
        else              ztp[n][q>>1] |= (zb << 16);
        float lnr = (KAr*Ar[n][q] + KBr*Br[n][q] + Kbr*btr[n] - mur)*isr*gvr[n] + bvr[n];
        float rhv = sigmoid_f(lnr) * hv;
        hb[swz(R, C)] = f2bf(rhv);          // in-place, unscaled
        acc = fmaf(rhv, rhv, acc);
      }
      float v2 = acc;
      v2 += __shfl_xor(v2,1); v2 += __shfl_xor(v2,2);
      v2 += __shfl_xor(v2,4); v2 += __shfl_xor(v2,8);
      if (lr == 0) REDZ[R][wc*8 + 7] = v2;
    }
  }
  __syncthreads();   // rh + |rh|^2 partials visible

  // ---- all-lane r2 mini-chain (short; off critical path) -> scq ----
  float scq[4];
  {
    int crow = lg*4 + (lr & 3);
    float s0 = REDZ[crow][7] + REDZ[crow][15] + REDZ[crow][23] + REDZ[crow][31];
    float wraw = sqrtf(s0); float wn = fmaxf(wraw, 1e-7f);
    float sv = tanh_f(wn / srow[2][crow] * srow[3][crow]);
    float sc = (wraw <= 1e-7f) ? 0.f : sv / wn;
    float rn = fmaxf((wraw <= 1e-7f) ? 0.f : fabsf(sv), 1e-7f);
    if (wc == 0 && lr < 4){ srow[4][crow] = rn; srow[5][crow] = artanh_f(rn); }
    #pragma unroll
    for (int q = 0; q < 4; ++q) scq[q] = __shfl(sc, (l & 48) + q);
  }

  // ================= h gate: single-stream GEMM on UNSCALED rh ============
  f32x4 Ah[4];
  float bth[4];
  #pragma unroll
  for (int n = 0; n < 4; ++n){
    int C = wc*64 + n*16 + lr;
    bth[n] = bias[HD + C];
    Ah[n] = (f32x4){0.f,0.f,0.f,0.f};
  }
  {
    const unsigned short* wHh = wbhh + 65536;
    #pragma unroll
    for (int s = 0; s < 8; ++s){
      int idx = lr*HD + (((4*s + lg) ^ (lr & 7)) << 3);
      bf16x8 ar = *(const bf16x8*)&hb[idx];
      #pragma unroll
      for (int n = 0; n < 4; ++n){
        int off = (((wc*4 + n)*8 + s)*64 + l)*8;
        bf16x8 bh = *(const bf16x8*)(wHh + off);
        Ah[n] = __builtin_amdgcn_mfma_f32_16x16x32_bf16(ar, bh, Ah[n], 0, 0, 0);
      }
    }
  }
  // fold mobius row-scale into Ah (row scaling commutes with W*v)
  #pragma unroll
  for (int n = 0; n < 4; ++n)
    #pragma unroll
    for (int q = 0; q < 4; ++q) Ah[n][q] *= scq[q];
  reduce7(Ah, Bh, bth, REDZ, wc, lr, lg);
  __syncthreads();
  if (t < BM){
    int R = t;
    float s[7];
    #pragma unroll
    for (int j = 0; j < 7; ++j)
      s[j] = REDZ[R][j] + REDZ[R][8+j] + REDZ[R][16+j] + REDZ[R][24+j];
    float o[5];
    chain5(s, sbb[1], sbb[5],
           srow[4][R], srow[5][R], srow[0][R], srow[1][R], o);
    #pragma unroll
    for (int k = 0; k < 5; ++k) kco[R][k] = o[k];
  }
  __syncthreads();
  // h phase3: u = tanh(ln) into Ah, |u|^2 partials
  {
    float gvh[4], bvh[4];
    #pragma unroll
    for (int n = 0; n < 4; ++n){
      int C = wc*64 + n*16 + lr;
      gvh[n] = gam[2*HD + C]; bvh[n] = bet[2*HD + C];
    }
    #pragma unroll
    for (int q = 0; q < 4; ++q){
      int R = lg*4 + q;
      float KA=kco[R][0], KB=kco[R][1], Kb=kco[R][2], mu=kco[R][3], is=kco[R][4];
      float acc = 0.f;
      #pragma unroll
      for (int n = 0; n < 4; ++n){
        float ln = (KA*Ah[n][q] + KB*Bh[n][q] + Kb*bth[n] - mu)*is*gvh[n] + bvh[n];
        float uv = tanh_f(ln);
        Ah[n][q] = uv;
        acc = fmaf(uv, uv, acc);
      }
      float v2 = acc;
      v2 += __shfl_xor(v2,1); v2 += __shfl_xor(v2,2);
      v2 += __shfl_xor(v2,4); v2 += __shfl_xor(v2,8);
      if (lr == 0) REDZ[R][wc*8] = v2;
    }
  }
  __syncthreads();
  if (t < BM){
    int R = t;
    float s0 = REDZ[R][0] + REDZ[R][8] + REDZ[R][16] + REDZ[R][24];
    float unraw = sqrtf(s0);
    float un = fmaxf(unraw, 1e-7f);
    float es = tanh_f(un) / un;
    float htn = fmaxf(es * unraw, 1e-7f);
    kco[R][0] = es; srow[6][R] = htn; srow[7][R] = artanh_f(htn);
  }
  __syncthreads();

  // ================= final combine =================
  #pragma unroll
  for (int q = 0; q < 4; ++q){
    int R = lg*4 + q;
    float es = kco[R][0];
    float a1 = 0.f, a2 = 0.f, a12 = 0.f;
    #pragma unroll
    for (int n = 0; n < 4; ++n){
      unsigned zp = ztp[n][q >> 1];
      float zv = __uint_as_float((q & 1) ? (zp & 0xFFFF0000u) : (zp << 16));
      float w2v = zv * es * Ah[n][q];
      float w1v = (1.f - zv) * hvreg[n][q];
      Ah[n][q] = w2v;
      Bh[n][q] = w1v;
      a1 = fmaf(w1v, w1v, a1); a2 = fmaf(w2v, w2v, a2); a12 = fmaf(w1v, w2v, a12);
    }
    float v1 = a1, v2 = a2, v3 = a12;
    v1 += __shfl_xor(v1,1); v2 += __shfl_xor(v2,1); v3 += __shfl_xor(v3,1);
    v1 += __shfl_xor(v1,2); v2 += __shfl_xor(v2,2); v3 += __shfl_xor(v3,2);
    v1 += __shfl_xor(v1,4); v2 += __shfl_xor(v2,4); v3 += __shfl_xor(v3,4);
    v1 += __shfl_xor(v1,8); v2 += __shfl_xor(v2,8); v3 += __shfl_xor(v3,8);
    if (lr == 0){
      REDZ[R][wc*8]   = v1;
      REDZ[R][wc*8+1] = v2;
      REDZ[R][wc*8+2] = v3;
    }
  }
  __syncthreads();
  if (t < BM){
    int R = t;
    float s1  = REDZ[R][0] + REDZ[R][8]  + REDZ[R][16] + REDZ[R][24];
    float s2  = REDZ[R][1] + REDZ[R][9]  + REDZ[R][17] + REDZ[R][25];
    float s12 = REDZ[R][2] + REDZ[R][10] + REDZ[R][18] + REDZ[R][26];
    float raw1 = sqrtf(s1); float n1 = fmaxf(raw1, 1e-7f);
    float ss1 = tanh_f(n1 / srow[2][R] * srow[3][R]);
    float sc1 = (raw1 <= 1e-7f) ? 0.f : ss1 / n1;
    float t1  = (raw1 <= 1e-7f) ? 0.f : ss1*ss1;
    float raw2 = sqrtf(s2); float n2 = fmaxf(raw2, 1e-7f);
    float ss2 = tanh_f(n2 / srow[6][R] * srow[7][R]);
    float sc2 = (raw2 <= 1e-7f) ? 0.f : ss2 / n2;
    float t2  = (raw2 <= 1e-7f) ? 0.f : ss2*ss2;
    float xy = sc1*sc2*s12;
    float ca = 1.f + 2.f*xy + t2;
    float cb = 1.f - t1;
    float den = fmaxf(1.f + 2.f*xy + t1*t2, 1e-15f);
    kco[R][0] = ca*sc1/den;
    kco[R][1] = cb*sc2/den;
  }
  __syncthreads();
  #pragma unroll
  for (int q = 0; q < 4; ++q){
    int R = lg*4 + q;
    float cw1 = kco[R][0], cw2 = kco[R][1];
    #pragma unroll
    for (int n = 0; n < 4; ++n){
      int C = wc*64 + n*16 + lr;
      out[(row0 + R)*HD + C] = cw1*Bh[n][q] + cw2*Ah[n][q];
    }
  }
}

extern "C" void kernel_launch(void* const* d_in, const int* in_sizes, int n_in,
                              void* d_out, int out_size, void* d_ws, size_t ws_size,
                              hipStream_t stream){
  const float* x    = (const float*)d_in[0];
  const float* hx   = (const float*)d_in[1];
  const float* Wih  = (const float*)d_in[2];
  const float* Whh  = (const float*)d_in[3];
  const float* bias = (const float*)d_in[4];
  const float* gam  = (const float*)d_in[5];
  const float* bet  = (const float*)d_in[6];
  float* out = (float*)d_out;
  unsigned short* wb = (unsigned short*)d_ws;
  const int B = in_sizes[0] / HD;

  hipLaunchKernelGGL(convert_w_kernel, dim3(192), dim3(256), 0, stream, Wih, Whh, wb);
  hipLaunchKernelGGL(mobius_gru_mfma, dim3(B / BM), dim3(NTH), 0, stream,
                     x, hx, wb, wb + 3*65536, bias, gam, bet, out, B);
}